// Round 13
// baseline (1266.764 us; speedup 1.0000x reference)
//
#include <hip/hip_runtime.h>
#include <math.h>

// Problem constants (match reference)
#define BATCH 16
#define NPTS  8192
#define FEATC 384
#define NG    512
#define KM    32

// d_out layout (flat float32, concatenated in return order)
#define OUT0_OFF 0                              // neighborhood [16,512,32,3]
#define OUT1_OFF (BATCH * NG * KM * 3)          // center       [16,512,3]
#define OUT2_OFF (OUT1_OFF + BATCH * NG * 3)    // feature_group[16,512,32,384]

// Disable FP contraction so mul/add rounding matches the numpy reference.
#pragma clang fp contract(off)

typedef float f32x2 __attribute__((ext_vector_type(2)));
typedef float f32x4 __attribute__((ext_vector_type(4)));

// ---------------------------------------------------------------------------
// DPP wave64 reductions (keys only). row_shr:1/2/4/8 fold each 16-lane row
// into its top lane; row_bcast:15/31 fold rows. Result valid in lane 63.
// ---------------------------------------------------------------------------
template <int CTRL>
__device__ __forceinline__ int dpp1(int x) {
    return __builtin_amdgcn_update_dpp(x, x, CTRL, 0xF, 0xF, false);
}

__device__ __forceinline__ unsigned long long wave_max_u64(unsigned long long k) {
    unsigned long long o;
#define STEP(C)                                                                \
    {                                                                          \
        unsigned lo = (unsigned)dpp1<C>((int)(unsigned)k);                     \
        unsigned hi = (unsigned)dpp1<C>((int)(unsigned)(k >> 32));             \
        o = ((unsigned long long)hi << 32) | lo;                               \
        if (o > k) k = o;                                                      \
    }
    STEP(0x111) STEP(0x112) STEP(0x114) STEP(0x118) STEP(0x142) STEP(0x143)
#undef STEP
    return k;                                   // lane 63 holds the max
}

__device__ __forceinline__ unsigned long long wave_min_u64(unsigned long long k) {
    unsigned long long o;
#define STEP(C)                                                                \
    {                                                                          \
        unsigned lo = (unsigned)dpp1<C>((int)(unsigned)k);                     \
        unsigned hi = (unsigned)dpp1<C>((int)(unsigned)(k >> 32));             \
        o = ((unsigned long long)hi << 32) | lo;                               \
        if (o < k) k = o;                                                      \
    }
    STEP(0x111) STEP(0x112) STEP(0x114) STEP(0x118) STEP(0x142) STEP(0x143)
#undef STEP
    return k;                                   // lane 63 holds the min
}

// Tree-min over an 8-entry register array (static indices after inlining).
__device__ __forceinline__ unsigned long long min8_u64(const unsigned long long* k) {
    unsigned long long t4[4];
#pragma unroll
    for (int i = 0; i < 4; ++i) t4[i] = k[i] < k[i + 4] ? k[i] : k[i + 4];
    unsigned long long a = t4[0] < t4[2] ? t4[0] : t4[2];
    unsigned long long b = t4[1] < t4[3] ? t4[1] : t4[3];
    return a < b ? a : b;
}

// ---------------------------------------------------------------------------
// Init kernel: zero the per-batch progress counters.
// ---------------------------------------------------------------------------
__global__ void init_progress(int* progress) {
    if (threadIdx.x < BATCH)
        __hip_atomic_store(&progress[threadIdx.x], 0,
                           __ATOMIC_RELAXED, __HIP_MEMORY_SCOPE_AGENT);
}

// ---------------------------------------------------------------------------
// Merged producer-consumer kernel, 1024-THREAD GEOMETRY: the producer's
// per-thread state (8 pts: X/Y/Z/MD = 32 VGPRs) fits the <=64-reg budget the
// 8192 consumer blocks need for 32 waves/CU — so the FPS loop state stays
// register-resident (no per-iteration spill-fills / sunk reloads), while
// consumers keep full occupancy (2 blocks x 1024 thr = 2048 thr/CU).
// L2 hygiene from rounds 10/11 retained (nt feature loads + nt output stores,
// low-rate spin).
//   blocks [0,16):        FPS producer (1024 thr, 16 waves).
//   blocks [16,16+8192):  consumer per (g,b) (g-major), 32-NN + gather.
// ---------------------------------------------------------------------------
__global__ __launch_bounds__(1024) void group_kernel(const float* __restrict__ xyz,
                                                     const float* __restrict__ features,
                                                     float* __restrict__ out0,
                                                     float* __restrict__ out1,
                                                     float* __restrict__ out2,
                                                     int* __restrict__ progress) {
#pragma clang fp contract(off)
    __shared__ unsigned long long sk[2][16];  // per-wave reduce slots (both roles)
    __shared__ int   sidx[KM];                // consumer: knn result indices
    __shared__ float scst[24];                // producer stash / consumer center

    const int tid  = threadIdx.x;
    const int lane = tid & 63;
    const int wid  = tid >> 6;                // 16 waves

    if (blockIdx.x < BATCH) {
        // ================= FPS producer =================
        __builtin_amdgcn_s_setprio(3);
        const int b = blockIdx.x;
        const float* xb = xyz + (size_t)b * NPTS * 3;
        float* co = out1 + (size_t)b * NG * 3;

        // 8 points per thread as 4 packed pairs (one-time global load).
        f32x2 X[4], Y[4], Z[4], MD[4];
#pragma unroll
        for (int j = 0; j < 4; ++j) {
            int p0 = tid + 2048 * j;
            int p1 = p0 + 1024;
            X[j]  = (f32x2){xb[p0 * 3 + 0], xb[p1 * 3 + 0]};
            Y[j]  = (f32x2){xb[p0 * 3 + 1], xb[p1 * 3 + 1]};
            Z[j]  = (f32x2){xb[p0 * 3 + 2], xb[p1 * 3 + 2]};
            MD[j] = (f32x2){1e10f, 1e10f};
        }

        int far = 0;
        for (int g = 0; g < NG; ++g) {
            // Broadcast load of current center coords (clean L2 => L2-hit).
            const float cx = xb[far * 3 + 0];
            const float cy = xb[far * 3 + 1];
            const float cz = xb[far * 3 + 2];
            if (tid == 0) {                   // stash center g for publication
                scst[(g & 7) * 3 + 0] = cx;
                scst[(g & 7) * 3 + 1] = cy;
                scst[(g & 7) * 3 + 2] = cz;
            }
            const f32x2 cx2 = (f32x2){cx, cx};
            const f32x2 cy2 = (f32x2){cy, cy};
            const f32x2 cz2 = (f32x2){cz, cz};

            // Exact min-dist update: ((dx*dx + dy*dy) + dz*dz), no fma.
#pragma unroll
            for (int j = 0; j < 4; ++j) {
                f32x2 dx = X[j] - cx2;
                f32x2 dy = Y[j] - cy2;
                f32x2 dz = Z[j] - cz2;
                f32x2 d  = (dx * dx + dy * dy) + dz * dz;
                MD[j] = __builtin_elementwise_min(MD[j], d);
            }
            // Per-lane max value (pure pk-max tree).
            f32x2 a0 = __builtin_elementwise_max(MD[0], MD[1]);
            f32x2 a1 = __builtin_elementwise_max(MD[2], MD[3]);
            f32x2 c0 = __builtin_elementwise_max(a0, a1);
            float lmax = fmaxf(c0.x, c0.y);

            // Smallest owned index attaining lmax (descending overwrite).
            unsigned candX = 0xFFFFFFFFu, candY = 0xFFFFFFFFu;
#pragma unroll
            for (int j = 3; j >= 0; --j) {
                if (MD[j].y == lmax) candY = (unsigned)(tid + 2048 * j + 1024);
                if (MD[j].x == lmax) candX = (unsigned)(tid + 2048 * j);
            }
            unsigned cand = candX < candY ? candX : candY;

            unsigned long long key =
                ((unsigned long long)__float_as_uint(lmax) << 32) | (unsigned)(~cand);
            key = wave_max_u64(key);          // lane 63 valid

            const int par = g & 1;
            if (lane == 63) sk[par][wid] = key;
            __syncthreads();

            // Tree over 16 wave slots (broadcast LDS reads).
            unsigned long long t[8];
#pragma unroll
            for (int w = 0; w < 8; ++w)
                t[w] = sk[par][w] > sk[par][w + 8] ? sk[par][w] : sk[par][w + 8];
            unsigned long long u0 = t[0] > t[4] ? t[0] : t[4];
            unsigned long long u1 = t[1] > t[5] ? t[1] : t[5];
            unsigned long long u2 = t[2] > t[6] ? t[2] : t[6];
            unsigned long long u3 = t[3] > t[7] ? t[3] : t[7];
            unsigned long long va = u0 > u2 ? u0 : u2;
            unsigned long long vb = u1 > u3 ? u1 : u3;
            unsigned long long gk = va > vb ? va : vb;
            far = (int)(~(unsigned)gk);

            // Batched publication: 8 centers + progress, first wave only.
            if ((g & 7) == 7) {
                if (tid < 24) co[(g - 7) * 3 + tid] = scst[tid];
                if (tid == 0)
                    __hip_atomic_store(&progress[b], g + 1,
                                       __ATOMIC_RELEASE, __HIP_MEMORY_SCOPE_AGENT);
            }
        }
        return;
    }

    // ================= consumer: KNN + gather for one (b,g) =================
    const int i = blockIdx.x - BATCH;
    const int b = i & 15;              // g-major: matches production order
    const int g = i >> 4;
    const int bgrow = b * NG + g;

    if (tid == 0) {
        while ((int)__hip_atomic_load(&progress[b], __ATOMIC_ACQUIRE,
                                      __HIP_MEMORY_SCOPE_AGENT) < g + 1)
            __builtin_amdgcn_s_sleep(127);    // low-rate spin: less L2 contention
        unsigned* co = (unsigned*)out1 + (size_t)bgrow * 3;
        scst[0] = __uint_as_float(__hip_atomic_load(co + 0, __ATOMIC_RELAXED,
                                                    __HIP_MEMORY_SCOPE_AGENT));
        scst[1] = __uint_as_float(__hip_atomic_load(co + 1, __ATOMIC_RELAXED,
                                                    __HIP_MEMORY_SCOPE_AGENT));
        scst[2] = __uint_as_float(__hip_atomic_load(co + 2, __ATOMIC_RELAXED,
                                                    __HIP_MEMORY_SCOPE_AGENT));
    }
    __syncthreads();

    const float cx = scst[0], cy = scst[1], cz = scst[2];
    const float q2 = (cx * cx + cy * cy) + cz * cz;   // plain add chain

    const float* xb = xyz + (size_t)b * NPTS * 3;

    // Exact distances for 8 points/thread, packed sortable u64 keys.
    unsigned long long k[8];
#pragma unroll
    for (int j = 0; j < 8; ++j) {
        int p = tid + (j << 10);
        float rx = xb[p * 3 + 0];
        float ry = xb[p * 3 + 1];
        float rz = xb[p * 3 + 2];
        float r2 = (rx * rx + ry * ry) + rz * rz;         // plain add chain
        float dot = fmaf(cz, rz, fmaf(cy, ry, cx * rx));  // fma chain (sgemm-style)
        float d = (q2 + r2) - 2.0f * dot;                 // identical to round 1
        unsigned u = __float_as_uint(d);
        u ^= ((unsigned)((int)u >> 31)) | 0x80000000u;    // sortable float
        k[j] = ((unsigned long long)u << 32) | (unsigned)p;
    }

    unsigned long long lv = min8_u64(k);
    // Per-wave cached min: lane 63 keeps wkey; LDS slots parity-double-buffered.
    unsigned long long wkey = wave_min_u64(lv);           // lane 63 valid
    if (lane == 63) sk[0][wid] = wkey;
    __syncthreads();

    for (int kk = 0; kk < KM; ++kk) {
        const int par = kk & 1;
        const int nxt = par ^ 1;
        // All threads: tree-min over the 16 cached wave keys.
        unsigned long long t[8];
#pragma unroll
        for (int w = 0; w < 8; ++w)
            t[w] = sk[par][w] < sk[par][w + 8] ? sk[par][w] : sk[par][w + 8];
        unsigned long long u0 = t[0] < t[4] ? t[0] : t[4];
        unsigned long long u1 = t[1] < t[5] ? t[1] : t[5];
        unsigned long long u2 = t[2] < t[6] ? t[2] : t[6];
        unsigned long long u3 = t[3] < t[7] ? t[3] : t[7];
        unsigned long long va = u0 < u2 ? u0 : u2;
        unsigned long long vb = u1 < u3 ? u1 : u3;
        unsigned long long gk = va < vb ? va : vb;
        const unsigned pt = (unsigned)gk;                 // low 32 = point idx
        const int wwave = (int)((pt & 1023u) >> 6);

        if (wid == wwave) {
            // Only the winning wave recomputes its reduction.
            if ((pt & 1023u) == (unsigned)tid) {
                sidx[kk] = (int)pt;
                const unsigned jw = pt >> 10;
#pragma unroll
                for (int j = 0; j < 8; ++j) {
                    if ((unsigned)j == jw) k[j] = ~0ULL;
                }
                lv = min8_u64(k);
            }
            wkey = wave_min_u64(lv);
            if (lane == 63) sk[nxt][wid] = wkey;
        } else {
            if (lane == 63) sk[nxt][wid] = wkey;          // re-publish cached key
        }
        __syncthreads();
    }

    // neighborhood: 32 x 3 = 96 floats (exact plain subtract, nt store).
    if (tid < 96) {
        int m = tid / 3;
        int c = tid - 3 * m;
        int p = sidx[m];
        float v = xb[p * 3 + c] - scst[c];
        __builtin_nontemporal_store(v, &out0[((size_t)bgrow * KM + m) * 3 + c]);
    }

    // features: 32 rows x 96 16B chunks = 3072, 3 per thread. Nontemporal on
    // BOTH sides: loads don't evict hot xyz from L2, stores don't allocate.
    const f32x4* fb = (const f32x4*)(features + (size_t)b * NPTS * FEATC);
    f32x4*       ob = (f32x4*)(out2 + (size_t)bgrow * KM * FEATC);
#pragma unroll
    for (int r = 0; r < 3; ++r) {
        int flat = tid + (r << 10);         // 0..3071
        int m  = flat / 96;
        int c4 = flat - 96 * m;
        f32x4 v = __builtin_nontemporal_load(&fb[(size_t)sidx[m] * 96 + c4]);
        __builtin_nontemporal_store(v, &ob[(size_t)m * 96 + c4]);
    }
}

extern "C" void kernel_launch(void* const* d_in, const int* in_sizes, int n_in,
                              void* d_out, int out_size, void* d_ws, size_t ws_size,
                              hipStream_t stream) {
    const float* xyz      = (const float*)d_in[0];
    const float* features = (const float*)d_in[1];
    float* out  = (float*)d_out;
    float* out0 = out + OUT0_OFF;   // neighborhood
    float* out1 = out + OUT1_OFF;   // center
    float* out2 = out + OUT2_OFF;   // feature_group

    int* progress = (int*)d_ws;     // 16 ints

    init_progress<<<1, 64, 0, stream>>>(progress);
    group_kernel<<<BATCH + BATCH * NG, 1024, 0, stream>>>(xyz, features,
                                                          out0, out1, out2,
                                                          progress);
}

// Round 14
// 620.219 us; speedup vs baseline: 2.0424x; 2.0424x over previous
//
#include <hip/hip_runtime.h>
#include <math.h>

// Problem constants (match reference)
#define BATCH 16
#define NPTS  8192
#define FEATC 384
#define NG    512
#define KM    32

// d_out layout (flat float32, concatenated in return order)
#define OUT0_OFF 0                              // neighborhood [16,512,32,3]
#define OUT1_OFF (BATCH * NG * KM * 3)          // center       [16,512,3]
#define OUT2_OFF (OUT1_OFF + BATCH * NG * 3)    // feature_group[16,512,32,384]

// Disable FP contraction so mul/add rounding matches the numpy reference.
#pragma clang fp contract(off)

typedef float f32x2 __attribute__((ext_vector_type(2)));
typedef float f32x4 __attribute__((ext_vector_type(4)));

// ---------------------------------------------------------------------------
// DPP wave64 reductions (keys only). row_shr:1/2/4/8 fold each 16-lane row
// into its top lane; row_bcast:15/31 fold rows. Result valid in lane 63.
// ---------------------------------------------------------------------------
template <int CTRL>
__device__ __forceinline__ int dpp1(int x) {
    return __builtin_amdgcn_update_dpp(x, x, CTRL, 0xF, 0xF, false);
}

__device__ __forceinline__ unsigned long long wave_max_u64(unsigned long long k) {
    unsigned long long o;
#define STEP(C)                                                                \
    {                                                                          \
        unsigned lo = (unsigned)dpp1<C>((int)(unsigned)k);                     \
        unsigned hi = (unsigned)dpp1<C>((int)(unsigned)(k >> 32));             \
        o = ((unsigned long long)hi << 32) | lo;                               \
        if (o > k) k = o;                                                      \
    }
    STEP(0x111) STEP(0x112) STEP(0x114) STEP(0x118) STEP(0x142) STEP(0x143)
#undef STEP
    return k;                                   // lane 63 holds the max
}

__device__ __forceinline__ unsigned long long wave_min_u64(unsigned long long k) {
    unsigned long long o;
#define STEP(C)                                                                \
    {                                                                          \
        unsigned lo = (unsigned)dpp1<C>((int)(unsigned)k);                     \
        unsigned hi = (unsigned)dpp1<C>((int)(unsigned)(k >> 32));             \
        o = ((unsigned long long)hi << 32) | lo;                               \
        if (o < k) k = o;                                                      \
    }
    STEP(0x111) STEP(0x112) STEP(0x114) STEP(0x118) STEP(0x142) STEP(0x143)
#undef STEP
    return k;                                   // lane 63 holds the min
}

// Tree-min over a 16-entry register array (static indices after inlining).
__device__ __forceinline__ unsigned long long min16_u64(const unsigned long long* k) {
    unsigned long long t8[8];
#pragma unroll
    for (int i = 0; i < 8; ++i) t8[i] = k[i] < k[i + 8] ? k[i] : k[i + 8];
    unsigned long long t4[4];
#pragma unroll
    for (int i = 0; i < 4; ++i) t4[i] = t8[i] < t8[i + 4] ? t8[i] : t8[i + 4];
    unsigned long long a = t4[0] < t4[2] ? t4[0] : t4[2];
    unsigned long long b = t4[1] < t4[3] ? t4[1] : t4[3];
    return a < b ? a : b;
}

// ---------------------------------------------------------------------------
// Init kernel: zero the per-batch progress counters.
// ---------------------------------------------------------------------------
__global__ void init_progress(int* progress) {
    if (threadIdx.x < BATCH)
        __hip_atomic_store(&progress[threadIdx.x], 0,
                           __ATOMIC_RELAXED, __HIP_MEMORY_SCOPE_AGENT);
}

// ---------------------------------------------------------------------------
// Merged producer-consumer kernel (round-12 consumer, unchanged) with a
// STREAMED producer: thread t owns points [16t,16t+16) whose coords are 48
// CONTIGUOUS floats (12 x dwordx4, 16B-aligned) — reloaded from the L2-hot
// xyz every iteration via coalesced vector loads issued at the TOP of the
// iteration (loop-invariant, independent of `far`), 2-chunk pipelined so
// live VGPRs stay ~54. Only MD (min-dist, 16 floats as 8 x f32x2) persists.
// L2 hygiene from rounds 10/11 retained.
//   blocks [0,16):        FPS producer (512 thr).
//   blocks [16,16+8192):  consumer per (g,b) (g-major), 32-NN + gather.
// ---------------------------------------------------------------------------
__global__ __launch_bounds__(512) void group_kernel(const float* __restrict__ xyz,
                                                    const float* __restrict__ features,
                                                    float* __restrict__ out0,
                                                    float* __restrict__ out1,
                                                    float* __restrict__ out2,
                                                    int* __restrict__ progress) {
#pragma clang fp contract(off)
    __shared__ unsigned long long sk[2][8];   // per-wave reduce slots (both roles)
    __shared__ int   sidx[KM];                // consumer: knn result indices
    __shared__ float scst[24];                // producer stash / consumer center

    const int tid  = threadIdx.x;
    const int lane = tid & 63;
    const int wid  = tid >> 6;                // 8 waves

    if (blockIdx.x < BATCH) {
        // ================= FPS producer (streamed coords) =================
        const int b = blockIdx.x;
        const float* xb = xyz + (size_t)b * NPTS * 3;
        float* co = out1 + (size_t)b * NG * 3;
        // Thread t owns points [16t, 16t+16): 48 contiguous floats, 16B-aligned.
        const f32x4* cb = (const f32x4*)(xb + 48 * tid);

        f32x2 MD[8];                          // pair u: points (16t+2u, 16t+2u+1)
#pragma unroll
        for (int u = 0; u < 8; ++u) MD[u] = (f32x2){1e10f, 1e10f};

        int far = 0;
        for (int g = 0; g < NG; ++g) {
            // Issue first two coord chunks (loop-invariant, L2-hot) early so
            // their latency hides under the center fetch below.
            f32x4 A0 = cb[0], A1 = cb[1], A2 = cb[2];      // points 0..3
            f32x4 B0 = cb[3], B1 = cb[4], B2 = cb[5];      // points 4..7

            // Broadcast load of current center coords (clean L2 => L2-hit).
            const float cx = xb[far * 3 + 0];
            const float cy = xb[far * 3 + 1];
            const float cz = xb[far * 3 + 2];
            if (tid == 0) {                   // stash center g for publication
                scst[(g & 7) * 3 + 0] = cx;
                scst[(g & 7) * 3 + 1] = cy;
                scst[(g & 7) * 3 + 2] = cz;
            }
            const f32x2 cx2 = (f32x2){cx, cx};
            const f32x2 cy2 = (f32x2){cy, cy};
            const f32x2 cz2 = (f32x2){cz, cz};

            // 4 chunks of 4 points, 2-deep pipelined. Exact math:
            // ((dx*dx + dy*dy) + dz*dz), packed pairs, no fma.
#pragma unroll
            for (int c = 0; c < 4; ++c) {
                // Current chunk in A0..A2 (floats f0..f11 = 4 points).
                f32x2 xl = (f32x2){A0.x, A0.w};            // x of p0,p1
                f32x2 yl = (f32x2){A0.y, A1.x};            // y of p0,p1
                f32x2 zl = (f32x2){A0.z, A1.y};            // z of p0,p1
                f32x2 xh = (f32x2){A1.z, A2.y};            // x of p2,p3
                f32x2 yh = (f32x2){A1.w, A2.z};            // y of p2,p3
                f32x2 zh = (f32x2){A2.x, A2.w};            // z of p2,p3
                // Rotate pipeline: A <- B, B <- next chunk (issue loads now).
                A0 = B0; A1 = B1; A2 = B2;
                if (c < 2) {
                    B0 = cb[3 * c + 6];
                    B1 = cb[3 * c + 7];
                    B2 = cb[3 * c + 8];
                }
                f32x2 dxl = xl - cx2, dyl = yl - cy2, dzl = zl - cz2;
                f32x2 dl  = (dxl * dxl + dyl * dyl) + dzl * dzl;
                MD[2 * c] = __builtin_elementwise_min(MD[2 * c], dl);
                f32x2 dxh = xh - cx2, dyh = yh - cy2, dzh = zh - cz2;
                f32x2 dh  = (dxh * dxh + dyh * dyh) + dzh * dzh;
                MD[2 * c + 1] = __builtin_elementwise_min(MD[2 * c + 1], dh);
            }

            // Per-lane max value (pure pk-max tree).
            f32x2 a0 = __builtin_elementwise_max(MD[0], MD[1]);
            f32x2 a1 = __builtin_elementwise_max(MD[2], MD[3]);
            f32x2 a2 = __builtin_elementwise_max(MD[4], MD[5]);
            f32x2 a3 = __builtin_elementwise_max(MD[6], MD[7]);
            f32x2 b0 = __builtin_elementwise_max(a0, a1);
            f32x2 b1 = __builtin_elementwise_max(a2, a3);
            f32x2 c0 = __builtin_elementwise_max(b0, b1);
            float lmax = fmaxf(c0.x, c0.y);

            // Smallest owned index attaining lmax (descending overwrite).
            unsigned cand = 0xFFFFFFFFu;
#pragma unroll
            for (int u = 7; u >= 0; --u) {
                if (MD[u].y == lmax) cand = (unsigned)(16 * tid + 2 * u + 1);
                if (MD[u].x == lmax) cand = (unsigned)(16 * tid + 2 * u);
            }

            unsigned long long key =
                ((unsigned long long)__float_as_uint(lmax) << 32) | (unsigned)(~cand);
            key = wave_max_u64(key);          // lane 63 valid

            const int par = g & 1;
            if (lane == 63) sk[par][wid] = key;
            __syncthreads();

            unsigned long long m0 = sk[par][0] > sk[par][1] ? sk[par][0] : sk[par][1];
            unsigned long long m1 = sk[par][2] > sk[par][3] ? sk[par][2] : sk[par][3];
            unsigned long long m2 = sk[par][4] > sk[par][5] ? sk[par][4] : sk[par][5];
            unsigned long long m3 = sk[par][6] > sk[par][7] ? sk[par][6] : sk[par][7];
            unsigned long long ma = m0 > m1 ? m0 : m1;
            unsigned long long mb = m2 > m3 ? m2 : m3;
            unsigned long long gk = ma > mb ? ma : mb;
            far = (int)(~(unsigned)gk);

            // Batched publication: 8 centers + progress, wave 0 only.
            if ((g & 7) == 7) {
                if (tid < 24) co[(g - 7) * 3 + tid] = scst[tid];
                if (tid == 0)
                    __hip_atomic_store(&progress[b], g + 1,
                                       __ATOMIC_RELEASE, __HIP_MEMORY_SCOPE_AGENT);
            }
        }
        return;
    }

    // ================= consumer: KNN + gather for one (b,g) =================
    const int i = blockIdx.x - BATCH;
    const int b = i & 15;              // g-major: matches production order
    const int g = i >> 4;
    const int bgrow = b * NG + g;

    if (tid == 0) {
        while ((int)__hip_atomic_load(&progress[b], __ATOMIC_ACQUIRE,
                                      __HIP_MEMORY_SCOPE_AGENT) < g + 1)
            __builtin_amdgcn_s_sleep(127);    // low-rate spin: less L2 contention
        unsigned* co = (unsigned*)out1 + (size_t)bgrow * 3;
        scst[0] = __uint_as_float(__hip_atomic_load(co + 0, __ATOMIC_RELAXED,
                                                    __HIP_MEMORY_SCOPE_AGENT));
        scst[1] = __uint_as_float(__hip_atomic_load(co + 1, __ATOMIC_RELAXED,
                                                    __HIP_MEMORY_SCOPE_AGENT));
        scst[2] = __uint_as_float(__hip_atomic_load(co + 2, __ATOMIC_RELAXED,
                                                    __HIP_MEMORY_SCOPE_AGENT));
    }
    __syncthreads();

    const float cx = scst[0], cy = scst[1], cz = scst[2];
    const float q2 = (cx * cx + cy * cy) + cz * cz;   // plain add chain

    const float* xb = xyz + (size_t)b * NPTS * 3;

    // Exact distances for 16 points/thread, packed sortable u64 keys.
    unsigned long long k[16];
#pragma unroll
    for (int j = 0; j < 16; ++j) {
        int p = tid + (j << 9);
        float rx = xb[p * 3 + 0];
        float ry = xb[p * 3 + 1];
        float rz = xb[p * 3 + 2];
        float r2 = (rx * rx + ry * ry) + rz * rz;         // plain add chain
        float dot = fmaf(cz, rz, fmaf(cy, ry, cx * rx));  // fma chain (sgemm-style)
        float d = (q2 + r2) - 2.0f * dot;                 // identical to round 1
        unsigned u = __float_as_uint(d);
        u ^= ((unsigned)((int)u >> 31)) | 0x80000000u;    // sortable float
        k[j] = ((unsigned long long)u << 32) | (unsigned)p;
    }

    unsigned long long lv = min16_u64(k);
    // Per-wave cached min: lane 63 keeps wkey; LDS slots parity-double-buffered.
    unsigned long long wkey = wave_min_u64(lv);           // lane 63 valid
    if (lane == 63) sk[0][wid] = wkey;
    __syncthreads();

    for (int kk = 0; kk < KM; ++kk) {
        const int par = kk & 1;
        const int nxt = par ^ 1;
        // All threads: tree-min over the 8 cached wave keys.
        unsigned long long m0 = sk[par][0] < sk[par][1] ? sk[par][0] : sk[par][1];
        unsigned long long m1 = sk[par][2] < sk[par][3] ? sk[par][2] : sk[par][3];
        unsigned long long m2 = sk[par][4] < sk[par][5] ? sk[par][4] : sk[par][5];
        unsigned long long m3 = sk[par][6] < sk[par][7] ? sk[par][6] : sk[par][7];
        unsigned long long ma = m0 < m1 ? m0 : m1;
        unsigned long long mb = m2 < m3 ? m2 : m3;
        unsigned long long gk = ma < mb ? ma : mb;
        const unsigned pt = (unsigned)gk;                 // low 32 = point idx
        const int wwave = (int)((pt & 511u) >> 6);

        if (wid == wwave) {
            // Only the winning wave recomputes its reduction.
            if ((pt & 511u) == (unsigned)tid) {
                sidx[kk] = (int)pt;
                const unsigned jw = pt >> 9;
#pragma unroll
                for (int j = 0; j < 16; ++j) {
                    if ((unsigned)j == jw) k[j] = ~0ULL;
                }
                lv = min16_u64(k);
            }
            wkey = wave_min_u64(lv);
            if (lane == 63) sk[nxt][wid] = wkey;
        } else {
            if (lane == 63) sk[nxt][wid] = wkey;          // re-publish cached key
        }
        __syncthreads();
    }

    // neighborhood: 32 x 3 = 96 floats (exact plain subtract, nt store).
    if (tid < 96) {
        int m = tid / 3;
        int c = tid - 3 * m;
        int p = sidx[m];
        float v = xb[p * 3 + c] - scst[c];
        __builtin_nontemporal_store(v, &out0[((size_t)bgrow * KM + m) * 3 + c]);
    }

    // features: 32 rows x 96 16B chunks, 6 per thread. Nontemporal on BOTH
    // sides: loads don't evict hot xyz from L2, stores don't allocate.
    const f32x4* fb = (const f32x4*)(features + (size_t)b * NPTS * FEATC);
    f32x4*       ob = (f32x4*)(out2 + (size_t)bgrow * KM * FEATC);
#pragma unroll
    for (int r = 0; r < 6; ++r) {
        int flat = tid + (r << 9);          // 0..3071
        int m  = flat / 96;
        int c4 = flat - 96 * m;
        f32x4 v = __builtin_nontemporal_load(&fb[(size_t)sidx[m] * 96 + c4]);
        __builtin_nontemporal_store(v, &ob[(size_t)m * 96 + c4]);
    }
}

extern "C" void kernel_launch(void* const* d_in, const int* in_sizes, int n_in,
                              void* d_out, int out_size, void* d_ws, size_t ws_size,
                              hipStream_t stream) {
    const float* xyz      = (const float*)d_in[0];
    const float* features = (const float*)d_in[1];
    float* out  = (float*)d_out;
    float* out0 = out + OUT0_OFF;   // neighborhood
    float* out1 = out + OUT1_OFF;   // center
    float* out2 = out + OUT2_OFF;   // feature_group

    int* progress = (int*)d_ws;     // 16 ints

    init_progress<<<1, 64, 0, stream>>>(progress);
    group_kernel<<<BATCH + BATCH * NG, 512, 0, stream>>>(xyz, features,
                                                         out0, out1, out2,
                                                         progress);
}